// Round 1
// baseline (134.412 us; speedup 1.0000x reference)
//
#include <hip/hip_runtime.h>

#define S_CACHE 32768
#define NQ 1024
#define D 128
#define T_TOT 33792
#define KVB 32
#define QBLK 64
#define NQT 16            // NQ / QBLK
#define TILES_TOTAL 1056  // T_TOT / KVB

typedef float f32x4 __attribute__((ext_vector_type(4)));
typedef short s16x8 __attribute__((ext_vector_type(8)));

static __device__ __forceinline__ unsigned short f2bf(float x) {
  unsigned int u = __float_as_uint(x);
  u += 0x7fffu + ((u >> 16) & 1u);
  return (unsigned short)(u >> 16);
}

// ---------------------------------------------------------------------------
// Main kernel: grid (NQT, ksplit), 256 threads (4 waves x 16 q-rows).
// Flash-decoding: each block handles QBLK q-rows vs a contiguous KV range,
// writes unnormalized partial O plus per-row (m, l) in log2 domain.
// ---------------------------------------------------------------------------
__global__ __launch_bounds__(256) void mt_attn_main(
    const float* __restrict__ qp, const float* __restrict__ knew,
    const float* __restrict__ vnew, const float* __restrict__ Kc,
    const float* __restrict__ Vc, float* __restrict__ ws,
    int ksplit, int tiles_pb)
{
  __shared__ __align__(16) unsigned char k_lds[KVB * 256];   // [32 key][128 d] bf16, XOR-swizzled 16B slots
  __shared__ __align__(16) unsigned char v_lds[D * 80];      // [128 dv][40 key] bf16, transposed + padded
  __shared__ __align__(16) unsigned char p_lds[4][16 * 80];  // per-wave P [16 q][40 key] bf16

  const int tid  = threadIdx.x;
  const int lane = tid & 63;
  const int w    = tid >> 6;
  const int qbase = blockIdx.x * QBLK;
  const int kbase = blockIdx.y * tiles_pb * KVB;

  // ---- Q fragments (MFMA A operand); fold 1/sqrt(128)*log2(e) into Q ----
  const float QSCALE = 0.0883883476483184f * 1.4426950408889634f;
  const int qr = qbase + w * 16 + (lane & 15);
  const int d0 = (lane >> 4) * 8;
  s16x8 qf[4];
#pragma unroll
  for (int c = 0; c < 4; ++c) {
    const float* src = qp + (size_t)qr * D + c * 32 + d0;
    f32x4 x0 = *(const f32x4*)(src);
    f32x4 x1 = *(const f32x4*)(src + 4);
#pragma unroll
    for (int j = 0; j < 4; ++j) {
      qf[c][j]     = (short)f2bf(x0[j] * QSCALE);
      qf[c][4 + j] = (short)f2bf(x1[j] * QSCALE);
    }
  }

  f32x4 oacc[8];
#pragma unroll
  for (int i = 0; i < 8; ++i) {
    f32x4 z = {0.f, 0.f, 0.f, 0.f};
    oacc[i] = z;
  }
  float mrun[4] = {-1e30f, -1e30f, -1e30f, -1e30f};
  float lrun[4] = {0.f, 0.f, 0.f, 0.f};

  // V staging map: thread handles key pair (2*p2, 2*p2+1), dv block dv0..dv0+7
  const int p2  = tid & 15;
  const int dv0 = (tid >> 4) * 8;

  for (int tile = 0; tile < tiles_pb; ++tile) {
    const int kt0 = kbase + tile * KVB;
    const bool in_cache = (kt0 < S_CACHE);  // uniform per tile (S, KVB both mult of 32)
    __syncthreads();  // all waves done reading previous tile's LDS

    // ---- stage K tile: [32][128] f32 -> bf16, swizzled 16B slots ----
    {
      const float* base = in_cache ? (Kc + (size_t)kt0 * D)
                                   : (knew + (size_t)(kt0 - S_CACHE) * D);
#pragma unroll
      for (int j = 0; j < 4; ++j) {
        int f   = tid + 256 * j;
        int row = f >> 5;
        int c4  = f & 31;
        f32x4 d4 = *(const f32x4*)(base + (size_t)row * D + c4 * 4);
        unsigned long long pk =
            (unsigned long long)f2bf(d4[0]) |
            ((unsigned long long)f2bf(d4[1]) << 16) |
            ((unsigned long long)f2bf(d4[2]) << 32) |
            ((unsigned long long)f2bf(d4[3]) << 48);
        int bo = (c4 * 8) ^ ((row & 7) << 4);
        *(unsigned long long*)(k_lds + row * 256 + bo) = pk;
      }
    }
    // ---- stage V tile transposed: v_lds[dv][key], rows padded to 80B ----
    {
      const float* base = in_cache ? (Vc + (size_t)kt0 * D)
                                   : (vnew + (size_t)(kt0 - S_CACHE) * D);
      const float* r0 = base + (size_t)(2 * p2) * D + dv0;
      const float* r1 = r0 + D;
      f32x4 a0 = *(const f32x4*)(r0);
      f32x4 a1 = *(const f32x4*)(r0 + 4);
      f32x4 b0 = *(const f32x4*)(r1);
      f32x4 b1 = *(const f32x4*)(r1 + 4);
#pragma unroll
      for (int m = 0; m < 4; ++m) {
        unsigned int lo = (unsigned int)f2bf(a0[m]) | ((unsigned int)f2bf(b0[m]) << 16);
        unsigned int hi = (unsigned int)f2bf(a1[m]) | ((unsigned int)f2bf(b1[m]) << 16);
        *(unsigned int*)(v_lds + (size_t)(dv0 + m) * 80 + p2 * 4) = lo;
        *(unsigned int*)(v_lds + (size_t)(dv0 + 4 + m) * 80 + p2 * 4) = hi;
      }
    }
    __syncthreads();

    // ---- QK^T: scores [16 q][32 key] in log2 units ----
    f32x4 sc[2];
#pragma unroll
    for (int h = 0; h < 2; ++h) {
      f32x4 z = {0.f, 0.f, 0.f, 0.f};
      sc[h] = z;
      const int row = h * 16 + (lane & 15);
      const unsigned char* krow = k_lds + row * 256;
      const int sw = (row & 7) << 4;
#pragma unroll
      for (int c = 0; c < 4; ++c) {
        s16x8 kf = *(const s16x8*)(krow + ((c * 64 + (lane >> 4) * 16) ^ sw));
        sc[h] = __builtin_amdgcn_mfma_f32_16x16x32_bf16(qf[c], kf, sc[h], 0, 0, 0);
      }
    }

    // ---- mask + online softmax (base-2) ----
    const int key0    = kt0 + (lane & 15);
    const int qrow_cd = qbase + w * 16 + (lane >> 4) * 4;  // + r
    float pv0[4], pv1[4];
#pragma unroll
    for (int r = 0; r < 4; ++r) {
      const int qg = qrow_cd + r;
      float s0 = sc[0][r];
      float s1 = sc[1][r];
      if (key0 >= S_CACHE && (key0 - S_CACHE) > qg) s0 = -1e30f;
      if (key0 + 16 >= S_CACHE && (key0 + 16 - S_CACHE) > qg) s1 = -1e30f;
      float vmax = fmaxf(s0, s1);
#pragma unroll
      for (int off = 1; off < 16; off <<= 1)
        vmax = fmaxf(vmax, __shfl_xor(vmax, off, 64));
      float mnew = fmaxf(mrun[r], vmax);
      float corr = exp2f(mrun[r] - mnew);
      float p0 = exp2f(s0 - mnew);
      float p1 = exp2f(s1 - mnew);
      float rs = p0 + p1;
#pragma unroll
      for (int off = 1; off < 16; off <<= 1)
        rs += __shfl_xor(rs, off, 64);
      lrun[r] = lrun[r] * corr + rs;
      mrun[r] = mnew;
      pv0[r] = p0;
      pv1[r] = p1;
#pragma unroll
      for (int cc = 0; cc < 8; ++cc) oacc[cc][r] *= corr;
    }

    // ---- P -> per-wave LDS (bf16), then read back in A-layout ----
    unsigned char* pw = p_lds[w];
    {
      const int qloc = (lane >> 4) * 4;
      const int kcol = (lane & 15);
#pragma unroll
      for (int r = 0; r < 4; ++r) {
        *(unsigned short*)(pw + (size_t)(qloc + r) * 80 + kcol * 2)        = f2bf(pv0[r]);
        *(unsigned short*)(pw + (size_t)(qloc + r) * 80 + (kcol + 16) * 2) = f2bf(pv1[r]);
      }
    }
    asm volatile("s_waitcnt lgkmcnt(0)" ::: "memory");
    s16x8 pf = *(const s16x8*)(pw + (size_t)(lane & 15) * 80 + (lane >> 4) * 16);

    // ---- PV: O[16 q][128 dv] += P @ V ----
    const unsigned char* vb = v_lds + (size_t)(lane & 15) * 80 + (lane >> 4) * 16;
#pragma unroll
    for (int cc = 0; cc < 8; ++cc) {
      s16x8 vf = *(const s16x8*)(vb + (size_t)cc * 16 * 80);
      oacc[cc] = __builtin_amdgcn_mfma_f32_16x16x32_bf16(pf, vf, oacc[cc], 0, 0, 0);
    }
  }

  // ---- write partial: O [64][128], m [64], l [64] ----
  const size_t pstride = (size_t)QBLK * D + 2 * QBLK;  // 8320 floats
  float* pbase = ws + (size_t)(blockIdx.x * ksplit + blockIdx.y) * pstride;
  float* Obase = pbase;
  float* mbase = pbase + (size_t)QBLK * D;
  float* lbase = mbase + QBLK;
  {
    const int qloc = w * 16 + (lane >> 4) * 4;
    const int col  = lane & 15;
#pragma unroll
    for (int r = 0; r < 4; ++r) {
#pragma unroll
      for (int cc = 0; cc < 8; ++cc)
        Obase[(size_t)(qloc + r) * D + cc * 16 + col] = oacc[cc][r];
      if (col == 0) {
        mbase[qloc + r] = mrun[r];
        lbase[qloc + r] = lrun[r];
      }
    }
  }
}

// ---------------------------------------------------------------------------
// Combine kernel: one thread per (row, dv).
// ---------------------------------------------------------------------------
__global__ __launch_bounds__(256) void mt_attn_combine(
    const float* __restrict__ ws, float* __restrict__ out, int ksplit)
{
  int idx  = blockIdx.x * 256 + threadIdx.x;
  int row  = idx >> 7;
  int dv   = idx & 127;
  int qt   = row >> 6;
  int qloc = row & 63;
  const size_t pstride = (size_t)QBLK * D + 2 * QBLK;
  const float* base = ws + (size_t)qt * ksplit * pstride;
  float mg = -1e30f;
  for (int b = 0; b < ksplit; ++b)
    mg = fmaxf(mg, base[(size_t)b * pstride + QBLK * D + qloc]);
  float L = 0.f, acc = 0.f;
  for (int b = 0; b < ksplit; ++b) {
    const float* pb = base + (size_t)b * pstride;
    float wgt = exp2f(pb[QBLK * D + qloc] - mg);
    L   += wgt * pb[QBLK * D + QBLK + qloc];
    acc += wgt * pb[(size_t)qloc * D + dv];
  }
  out[(size_t)row * D + dv] = acc / L;
}

extern "C" void kernel_launch(void* const* d_in, const int* in_sizes, int n_in,
                              void* d_out, int out_size, void* d_ws, size_t ws_size,
                              hipStream_t stream)
{
  const float* qp = (const float*)d_in[0];
  const float* kp = (const float*)d_in[1];
  const float* vp = (const float*)d_in[2];
  const float* Kc = (const float*)d_in[3];
  const float* Vc = (const float*)d_in[4];
  float* out = (float*)d_out;
  float* ws  = (float*)d_ws;

  const size_t pstride_bytes = ((size_t)QBLK * D + 2 * QBLK) * sizeof(float);
  static const int cands[] = {66, 48, 44, 33, 32, 24, 22, 16, 12, 11, 8, 6, 4, 3, 2, 1};
  int ksplit = 1;
  for (int i = 0; i < 16; ++i) {
    if ((size_t)NQT * cands[i] * pstride_bytes <= ws_size) { ksplit = cands[i]; break; }
  }
  int tiles_pb = TILES_TOTAL / ksplit;

  dim3 grid(NQT, ksplit);
  mt_attn_main<<<grid, dim3(256), 0, stream>>>(qp, kp, vp, Kc, Vc, ws, ksplit, tiles_pb);
  mt_attn_combine<<<dim3((NQ * D) / 256), dim3(256), 0, stream>>>(ws, out, ksplit);
}

// Round 2
// 107.493 us; speedup vs baseline: 1.2504x; 1.2504x over previous
//
#include <hip/hip_runtime.h>

#define S_CACHE 32768
#define NQ 1024
#define D 128
#define KVB 32
#define TILES_TOTAL 1056

typedef float f32x4 __attribute__((ext_vector_type(4)));
typedef short s16x8 __attribute__((ext_vector_type(8)));
typedef int   i32x4 __attribute__((ext_vector_type(4)));

static __device__ __forceinline__ int cvtpk(float lo, float hi) {
  int r;
  asm("v_cvt_pk_bf16_f32 %0, %1, %2" : "=v"(r) : "v"(lo), "v"(hi));
  return r;
}
static __device__ __forceinline__ s16x8 frag4(int a, int b, int c, int d) {
  i32x4 t = {a, b, c, d};
  return __builtin_bit_cast(s16x8, t);
}

// ---------------------------------------------------------------------------
// Main kernel: grid (8, ksplit), 256 threads = 4 waves, each wave owns 32 q.
// Swapped-operand flash attention:
//   S^T = mfma(A=K, B=Q^T)  -> lane(g,qq) holds P[q=qq][keys 8g..8g+7] locally
//   O^T = mfma(A=V^T, B=P^T)
// K staged with key permutation kit(h,qq)=8*(qq>>2)+4h+(qq&3) so a lane's
// 8 score regs are exactly the 8 consecutive keys its PV B-fragment needs.
// LDS is fragment-linear: all ds reads/writes are b128 at lane*16.
// ---------------------------------------------------------------------------
__global__ __launch_bounds__(256, 2) void mt_attn_main(
    const float* __restrict__ qp, const float* __restrict__ knew,
    const float* __restrict__ vnew, const float* __restrict__ Kc,
    const float* __restrict__ Vc, float* __restrict__ ws,
    int ksplit, int tiles_pb)
{
  __shared__ __align__(16) unsigned char k_lds[2][8192];  // 8 frags (h,c) x 64 lanes x 16B
  __shared__ __align__(16) unsigned char v_lds[2][8192];  // 8 frags (dt)  x 64 lanes x 16B

  const int tid  = threadIdx.x;
  const int lane = tid & 63;
  const int w    = tid >> 6;
  const int g    = lane >> 4;
  const int qq   = lane & 15;
  const int qg32 = blockIdx.x * 4 + w;  // 0..31, 32 q-rows each
  const int split = blockIdx.y;
  const int kbase = split * tiles_pb * KVB;

  // ---- Q fragments (B-operand): lane holds Q[q][32c+8g+i], i=0..7, scaled ----
  const float QSCALE = 0.0883883476483184f * 1.4426950408889634f;  // 1/sqrt(128)*log2(e)
  s16x8 qf[2][4];
#pragma unroll
  for (int u = 0; u < 2; ++u) {
    const float* qrow = qp + (size_t)(qg32 * 32 + u * 16 + qq) * D + 8 * g;
#pragma unroll
    for (int c = 0; c < 4; ++c) {
      f32x4 x0 = *(const f32x4*)(qrow + 32 * c);
      f32x4 x1 = *(const f32x4*)(qrow + 32 * c + 4);
      qf[u][c] = frag4(cvtpk(x0[0] * QSCALE, x0[1] * QSCALE),
                       cvtpk(x0[2] * QSCALE, x0[3] * QSCALE),
                       cvtpk(x1[0] * QSCALE, x1[1] * QSCALE),
                       cvtpk(x1[2] * QSCALE, x1[3] * QSCALE));
    }
  }

  f32x4 oacc[2][8];
#pragma unroll
  for (int u = 0; u < 2; ++u)
#pragma unroll
    for (int dt = 0; dt < 8; ++dt) {
      f32x4 z = {0.f, 0.f, 0.f, 0.f};
      oacc[u][dt] = z;
    }
  float mrun[2] = {-1e30f, -1e30f};
  float lrun[2] = {0.f, 0.f};

  // staging geometry (per thread): K chunks (h=0/1, c=w, lane), V chunks (dt=w, w+4, lane)
  const int kitr = 8 * (qq >> 2) + (qq & 3);  // K source row slot (h=0); h=1 adds +4
  const int kcol = 32 * w + 8 * g;

  f32x4 ka[4];
  float va[16];

  // ---- stage loader: issue global loads for tile t32 ----
  auto stage_load = [&](int t32) {
    const float* kb_;
    const float* vb_;
    if (t32 < S_CACHE) {
      kb_ = Kc + (size_t)t32 * D;
      vb_ = Vc + (size_t)t32 * D;
    } else {
      kb_ = knew + (size_t)(t32 - S_CACHE) * D;
      vb_ = vnew + (size_t)(t32 - S_CACHE) * D;
    }
    ka[0] = *(const f32x4*)(kb_ + (size_t)kitr * D + kcol);
    ka[1] = *(const f32x4*)(kb_ + (size_t)kitr * D + kcol + 4);
    ka[2] = *(const f32x4*)(kb_ + (size_t)(kitr + 4) * D + kcol);
    ka[3] = *(const f32x4*)(kb_ + (size_t)(kitr + 4) * D + kcol + 4);
#pragma unroll
    for (int j = 0; j < 2; ++j) {
      const int dt = w + 4 * j;
#pragma unroll
      for (int i = 0; i < 8; ++i)
        va[8 * j + i] = vb_[(size_t)(8 * g + i) * D + 16 * dt + qq];
    }
  };

  // ---- stage writer: convert + ds_write_b128 fragment-linear ----
  auto stage_write = [&](int b) {
    i32x4 kc0 = {cvtpk(ka[0][0], ka[0][1]), cvtpk(ka[0][2], ka[0][3]),
                 cvtpk(ka[1][0], ka[1][1]), cvtpk(ka[1][2], ka[1][3])};
    *(i32x4*)(&k_lds[b][(size_t)((w)*64 + lane) * 16]) = kc0;
    i32x4 kc1 = {cvtpk(ka[2][0], ka[2][1]), cvtpk(ka[2][2], ka[2][3]),
                 cvtpk(ka[3][0], ka[3][1]), cvtpk(ka[3][2], ka[3][3])};
    *(i32x4*)(&k_lds[b][(size_t)((4 + w) * 64 + lane) * 16]) = kc1;
#pragma unroll
    for (int j = 0; j < 2; ++j) {
      i32x4 vc = {cvtpk(va[8 * j + 0], va[8 * j + 1]), cvtpk(va[8 * j + 2], va[8 * j + 3]),
                  cvtpk(va[8 * j + 4], va[8 * j + 5]), cvtpk(va[8 * j + 6], va[8 * j + 7])};
      *(i32x4*)(&v_lds[b][(size_t)((w + 4 * j) * 64 + lane) * 16]) = vc;
    }
  };

  // prologue: stage tile 0 into buf 0
  stage_load(kbase);
  stage_write(0);
  int cur = 0;

  for (int tile = 0; tile < tiles_pb; ++tile) {
    const int t32 = kbase + tile * KVB;
    __syncthreads();  // stage(tile) visible; prior-buf reads done

    const bool havenext = (tile + 1 < tiles_pb);
    if (havenext) stage_load(t32 + KVB);  // T14: issue loads early

    // ---- QK^T (swapped): sc[u][h], C col=qq(q), row=4g+r (key 8g+4h+r) ----
    f32x4 sc[2][2];
#pragma unroll
    for (int u = 0; u < 2; ++u)
#pragma unroll
      for (int h = 0; h < 2; ++h) {
        f32x4 z = {0.f, 0.f, 0.f, 0.f};
        sc[u][h] = z;
      }
#pragma unroll
    for (int h = 0; h < 2; ++h)
#pragma unroll
      for (int c = 0; c < 4; ++c) {
        s16x8 kf = *(const s16x8*)(&k_lds[cur][(size_t)((h * 4 + c) * 64 + lane) * 16]);
        sc[0][h] = __builtin_amdgcn_mfma_f32_16x16x32_bf16(kf, qf[0][c], sc[0][h], 0, 0, 0);
        sc[1][h] = __builtin_amdgcn_mfma_f32_16x16x32_bf16(kf, qf[1][c], sc[1][h], 0, 0, 0);
      }

    // ---- softmax (base-2, lane-local rows) + P fragments ----
    s16x8 pf[2];
#pragma unroll
    for (int u = 0; u < 2; ++u) {
      float s[8];
#pragma unroll
      for (int h = 0; h < 2; ++h)
#pragma unroll
        for (int r = 0; r < 4; ++r)
          s[4 * h + r] = sc[u][h][r];
      if (t32 >= S_CACHE) {  // causal mask inside the new block (uniform branch)
        const int qglob = qg32 * 32 + u * 16 + qq;
#pragma unroll
        for (int n = 0; n < 8; ++n) {
          const int key = t32 + 8 * g + n;
          if (key - S_CACHE > qglob) s[n] = -1e30f;
        }
      }
      float vmax = fmaxf(fmaxf(fmaxf(s[0], s[1]), fmaxf(s[2], s[3])),
                         fmaxf(fmaxf(s[4], s[5]), fmaxf(s[6], s[7])));
      vmax = fmaxf(vmax, __shfl_xor(vmax, 16, 64));
      vmax = fmaxf(vmax, __shfl_xor(vmax, 32, 64));
      if (!__all(vmax <= mrun[u] + 8.f)) {  // T13 defer-max
        const float mnew = fmaxf(mrun[u], vmax);
        const float corr = exp2f(mrun[u] - mnew);
        lrun[u] *= corr;
#pragma unroll
        for (int dt = 0; dt < 8; ++dt) oacc[u][dt] *= corr;
        mrun[u] = mnew;
      }
      float p[8], rs = 0.f;
#pragma unroll
      for (int n = 0; n < 8; ++n) {
        p[n] = exp2f(s[n] - mrun[u]);
        rs += p[n];
      }
      rs += __shfl_xor(rs, 16, 64);
      rs += __shfl_xor(rs, 32, 64);
      lrun[u] += rs;
      pf[u] = frag4(cvtpk(p[0], p[1]), cvtpk(p[2], p[3]),
                    cvtpk(p[4], p[5]), cvtpk(p[6], p[7]));
    }

    // ---- PV (swapped): O^T += V^T @ P^T ----
#pragma unroll
    for (int dt = 0; dt < 8; ++dt) {
      s16x8 vf = *(const s16x8*)(&v_lds[cur][(size_t)(dt * 64 + lane) * 16]);
      oacc[0][dt] = __builtin_amdgcn_mfma_f32_16x16x32_bf16(vf, pf[0], oacc[0][dt], 0, 0, 0);
      oacc[1][dt] = __builtin_amdgcn_mfma_f32_16x16x32_bf16(vf, pf[1], oacc[1][dt], 0, 0, 0);
    }

    if (havenext) stage_write(cur ^ 1);  // convert + write after compute
    cur ^= 1;
  }

  // ---- write partial: O^T [128 dv][32 q] + m[32] + l[32]  (4160 floats) ----
  float* pbase = ws + (size_t)(qg32 * ksplit + split) * 4160;
#pragma unroll
  for (int u = 0; u < 2; ++u) {
#pragma unroll
    for (int dt = 0; dt < 8; ++dt)
#pragma unroll
      for (int r = 0; r < 4; ++r)
        pbase[(size_t)(16 * dt + 4 * g + r) * 32 + u * 16 + qq] = oacc[u][dt][r];
    if (g == 0) {
      pbase[4096 + u * 16 + qq] = mrun[u];
      pbase[4128 + u * 16 + qq] = lrun[u];
    }
  }
}

// ---------------------------------------------------------------------------
// Combine: one thread per (q, dv); coalesced partial reads (ql fastest).
// ---------------------------------------------------------------------------
__global__ __launch_bounds__(256) void mt_attn_combine(
    const float* __restrict__ ws, float* __restrict__ out, int ksplit)
{
  const int t  = blockIdx.x * 256 + threadIdx.x;  // 131072 total
  const int ql = t & 31;
  const int dv = (t >> 5) & 127;
  const int qg = t >> 12;
  const float* base = ws + (size_t)qg * ksplit * 4160;
  float mg = -1e30f;
  for (int s = 0; s < ksplit; ++s)
    mg = fmaxf(mg, base[(size_t)s * 4160 + 4096 + ql]);
  float L = 0.f, acc = 0.f;
  for (int s = 0; s < ksplit; ++s) {
    const float* pb = base + (size_t)s * 4160;
    const float wgt = exp2f(pb[4096 + ql] - mg);
    L   += wgt * pb[4128 + ql];
    acc += wgt * pb[(size_t)dv * 32 + ql];
  }
  out[(size_t)(qg * 32 + ql) * D + dv] = acc / L;
}

extern "C" void kernel_launch(void* const* d_in, const int* in_sizes, int n_in,
                              void* d_out, int out_size, void* d_ws, size_t ws_size,
                              hipStream_t stream)
{
  const float* qp = (const float*)d_in[0];
  const float* kp = (const float*)d_in[1];
  const float* vp = (const float*)d_in[2];
  const float* Kc = (const float*)d_in[3];
  const float* Vc = (const float*)d_in[4];
  float* out = (float*)d_out;
  float* ws  = (float*)d_ws;

  // partial footprint: 32 qgroups x ksplit x 4160 floats = ksplit * 532480 B
  static const int cands[] = {66, 48, 44, 33, 32, 24, 22, 16, 12, 11, 8, 6, 4, 3, 2, 1};
  int ksplit = 1;
  for (int i = 0; i < 16; ++i) {
    if ((size_t)cands[i] * 532480u <= ws_size) { ksplit = cands[i]; break; }
  }
  const int tiles_pb = TILES_TOTAL / ksplit;

  mt_attn_main<<<dim3(8, ksplit), dim3(256), 0, stream>>>(qp, kp, vp, Kc, Vc, ws,
                                                          ksplit, tiles_pb);
  mt_attn_combine<<<dim3((NQ * D) / 256), dim3(256), 0, stream>>>(ws, out, ksplit);
}